// Round 1
// baseline (1558.839 us; speedup 1.0000x reference)
//
#include <hip/hip_runtime.h>
#include <stdint.h>

// PolicyCoreRNN: LSTM, B=1024, T=64, H=I=512.
// Plan: prep kernel packs W=[W_ih;W_hh] (bf16, MFMA-fragment-major), h0 (bf16
// frag-major), c0 (f32 D-frag-major), bias=b_ih+b_hh. Then 64 sequential step
// kernels (grid sync via stream order): each does gates = [x_t,h] @ W^T with
// 16x16x32 bf16 MFMA (K=1024), fused LSTM cell + mask fold-in + all outputs.
//
// ws layout (bytes), total ~7.2 MB:
#define WC_OFF   0u          // 4096 frags * 1024B = 4 MiB   bf16 W frag-major
#define HF_OFF   4194304u    // 1024 frags * 1024B = 1 MiB   bf16 h state
#define CF_OFF   5242880u    // 2048 frags * 1024B = 2 MiB   f32 c state
#define BIAS_OFF 7340032u    // 2048 f32
// out (f32 elements): x | new_rnn_states | h_stack | c_stack
#define OUT_RNN  33554432u
#define OUT_HS   34603008u
#define OUT_CS   68157440u

typedef __attribute__((ext_vector_type(4))) float f32x4;
typedef __attribute__((ext_vector_type(8))) short s16x8;
typedef __attribute__((ext_vector_type(4))) unsigned int u32x4;

__device__ __forceinline__ unsigned short f2bf(float f) {
  union { float f; unsigned int u; } v; v.f = f;
  return (unsigned short)((v.u + 0x7FFFu + ((v.u >> 16) & 1u)) >> 16);
}
__device__ __forceinline__ unsigned int pack2(float a, float b) {
  return (unsigned int)f2bf(a) | ((unsigned int)f2bf(b) << 16);
}
__device__ __forceinline__ float sigm(float x) { return 1.0f / (1.0f + __expf(-x)); }

__device__ __forceinline__ void gl_lds16(const void* g, void* lds) {
  __builtin_amdgcn_global_load_lds(
      (const __attribute__((address_space(1))) unsigned int*)g,
      (__attribute__((address_space(3))) unsigned int*)lds, 16, 0, 0);
}

// Fragment conventions (16x16x32 bf16 MFMA):
//  A/B input frag: lane l holds index (l&15) of the 16-dim, k-slot (l>>4)*8+e.
//  (A and B share the same k-slot map, so any consistent k permutation is OK.)
//  D frag: col = l&15 (B dim), row = (l>>4)*4 + reg (A dim).   [m89-verified]

__global__ void __launch_bounds__(256) prep_kernel(
    const float* __restrict__ rnn, const float* __restrict__ Wih,
    const float* __restrict__ Whh, const float* __restrict__ bih,
    const float* __restrict__ bhh, unsigned char* __restrict__ ws) {
  unsigned int tid = blockIdx.x * 256u + threadIdx.x;
  unsigned short* wcf = (unsigned short*)(ws + WC_OFF);
  unsigned short* hf  = (unsigned short*)(ws + HF_OFF);
  float* cf   = (float*)(ws + CF_OFF);
  float* bias = (float*)(ws + BIAS_OFF);
  if (tid < 262144u) {
    // W frags: frag=(cb in [0,128), ks in [0,32)); gatecol=cb*16+(l&15); k0=ks*32+(l>>4)*8
    unsigned int frag = tid >> 6, l = tid & 63u;
    unsigned int cb = frag >> 5, ks = frag & 31u;
    unsigned int g  = cb * 16u + (l & 15u);
    unsigned int k0 = ks * 32u + ((l >> 4) << 3);
    const float* src = (k0 < 512u) ? (Wih + g * 512u + k0) : (Whh + g * 512u + (k0 - 512u));
    u32x4 p;
    p.x = pack2(src[0], src[1]); p.y = pack2(src[2], src[3]);
    p.z = pack2(src[4], src[5]); p.w = pack2(src[6], src[7]);
    *(u32x4*)(wcf + (size_t)frag * 512u + l * 8u) = p;
  } else if (tid < 327680u) {
    // h0 frags: frag=(mb in [0,64), ks in [0,16)); b=mb*16+(l&15); hcol0=ks*32+(l>>4)*8
    unsigned int t2 = tid - 262144u;
    unsigned int frag = t2 >> 6, l = t2 & 63u;
    unsigned int mb = frag >> 4, ks = frag & 15u;
    unsigned int b  = mb * 16u + (l & 15u);
    unsigned int c0 = ks * 32u + ((l >> 4) << 3);
    const float* src = rnn + (size_t)b * 1024u + c0;
    u32x4 p;
    p.x = pack2(src[0], src[1]); p.y = pack2(src[2], src[3]);
    p.z = pack2(src[4], src[5]); p.w = pack2(src[6], src[7]);
    *(u32x4*)(hf + (size_t)frag * 512u + l * 8u) = p;
  } else if (tid < 458752u) {
    // c0 frags (D layout): frag=(mb in [0,64), cfi in [0,32)); b=mb*16+(l>>4)*4+r; hcol=cfi*16+(l&15)
    unsigned int t2 = tid - 327680u;
    unsigned int frag = t2 >> 6, l = t2 & 63u;
    unsigned int mb = frag >> 5, cfi = frag & 31u;
    unsigned int hcol = cfi * 16u + (l & 15u);
    f32x4 p;
    #pragma unroll
    for (int r = 0; r < 4; ++r) {
      unsigned int b = mb * 16u + ((l >> 4) << 2) + r;
      p[r] = rnn[(size_t)b * 1024u + 512u + hcol];
    }
    *(f32x4*)(cf + (size_t)frag * 256u + l * 4u) = p;
  } else if (tid < 460800u) {
    unsigned int g = tid - 458752u;
    bias[g] = bih[g] + bhh[g];
  }
}

// Step kernel: grid 256 blocks = (mt in [0,16)) x (ht in [0,16)); 256 threads (4 waves).
// Block tile: 64 batch rows x 32 h-cols (=> 128 gate cols spread over 4 gates).
// Wave w: m-half mh=w&1 (32 rows), col-half ch=w>>1 (16 h-cols), all 4 gates in-register.
__global__ void __launch_bounds__(256) step_kernel(
    const float* __restrict__ xg, const float* __restrict__ dones,
    unsigned char* __restrict__ ws, float* __restrict__ out, int t) {
  const unsigned short* wcf = (const unsigned short*)(ws + WC_OFF);
  unsigned short* hf = (unsigned short*)(ws + HF_OFF);
  float* cf = (float*)(ws + CF_OFF);
  const float* bias = (const float*)(ws + BIAS_OFF);

  __shared__ __align__(16) unsigned char smem[49152];
  // Abuf: smem + buf*8192, 8 frags x 1KB  (A tile 64 x 64k)
  // Bbuf: smem + 16384 + buf*16384, 16 frags x 1KB (B tile 128 gatecols x 64k)

  const int tid = threadIdx.x;
  const int w = tid >> 6, l = tid & 63;
  const int mh = w & 1, ch = w >> 1;
  const int mt = (int)blockIdx.x >> 4, ht = (int)blockIdx.x & 15;

  f32x4 acc[2][4];
  {
    f32x4 z = {0.f, 0.f, 0.f, 0.f};
    #pragma unroll
    for (int i = 0; i < 2; ++i)
      #pragma unroll
      for (int j = 0; j < 4; ++j) acc[i][j] = z;
  }

  f32x4 xv[2][2]; // staged x values (async split: load early, ds_write after MFMA)

  auto stage_load = [&](int kc, int buf) {
    // B: 16 frags; wave w issues 4. idx: g=idx>>2, cbl=(idx>>1)&1, ksl=idx&1
    unsigned char* bb = smem + 16384 + buf * 16384;
    #pragma unroll
    for (int j = 0; j < 4; ++j) {
      int idx = w * 4 + j;
      int g = idx >> 2, cbl = (idx >> 1) & 1, ksl = idx & 1;
      int cb = g * 32 + ht * 2 + cbl;
      int ks = kc * 2 + ksl;
      const unsigned short* src = wcf + ((size_t)(cb * 32 + ks) * 64u + l) * 8u;
      gl_lds16(src, bb + idx * 1024);
    }
    unsigned char* ab = smem + buf * 8192;
    if (kc >= 8) {
      // h part: frag-major bf16 state, direct global_load_lds
      #pragma unroll
      for (int j = 0; j < 2; ++j) {
        int idx = w * 2 + j;          // mb = w, ksl = j
        int ksh = (kc - 8) * 2 + j;
        int mb_abs = mt * 4 + w;
        const unsigned short* src = hf + ((size_t)(mb_abs * 16 + ksh) * 64u + l) * 8u;
        gl_lds16(src, ab + idx * 1024);
      }
    } else {
      // x part: gather 8 consecutive f32 per lane (cvt+write deferred)
      #pragma unroll
      for (int j = 0; j < 2; ++j) {
        int ks = kc * 2 + j;
        int b = mt * 64 + w * 16 + (l & 15);
        int k0 = ks * 32 + ((l >> 4) << 3);
        const float* src = xg + ((size_t)(b * 64 + t)) * 512u + k0;
        xv[j][0] = *(const f32x4*)src;
        xv[j][1] = *(const f32x4*)(src + 4);
      }
    }
  };
  auto stage_write = [&](int kc, int buf) {
    if (kc < 8) {
      unsigned char* ab = smem + buf * 8192;
      #pragma unroll
      for (int j = 0; j < 2; ++j) {
        int idx = w * 2 + j;
        u32x4 p;
        p.x = pack2(xv[j][0].x, xv[j][0].y); p.y = pack2(xv[j][0].z, xv[j][0].w);
        p.z = pack2(xv[j][1].x, xv[j][1].y); p.w = pack2(xv[j][1].z, xv[j][1].w);
        *(u32x4*)(ab + idx * 1024 + l * 16) = p;
      }
    }
  };

  stage_load(0, 0);
  stage_write(0, 0);
  __syncthreads();

  for (int kc = 0; kc < 16; ++kc) {
    int cur = kc & 1;
    if (kc < 15) stage_load(kc + 1, cur ^ 1);
    unsigned char* ab = smem + cur * 8192;
    unsigned char* bb = smem + 16384 + cur * 16384;
    s16x8 afr[2][2], bfr[4][2];
    #pragma unroll
    for (int mb2 = 0; mb2 < 2; ++mb2)
      #pragma unroll
      for (int ksl = 0; ksl < 2; ++ksl)
        afr[mb2][ksl] = *(const s16x8*)(ab + ((mh * 2 + mb2) * 2 + ksl) * 1024 + l * 16);
    #pragma unroll
    for (int g = 0; g < 4; ++g)
      #pragma unroll
      for (int ksl = 0; ksl < 2; ++ksl)
        bfr[g][ksl] = *(const s16x8*)(bb + (g * 4 + ch * 2 + ksl) * 1024 + l * 16);
    #pragma unroll
    for (int mb2 = 0; mb2 < 2; ++mb2)
      #pragma unroll
      for (int g = 0; g < 4; ++g)
        #pragma unroll
        for (int ksl = 0; ksl < 2; ++ksl)
          acc[mb2][g] = __builtin_amdgcn_mfma_f32_16x16x32_bf16(
              afr[mb2][ksl], bfr[g][ksl], acc[mb2][g], 0, 0, 0);
    if (kc < 15) stage_write(kc + 1, cur ^ 1);
    __syncthreads();
  }

  // ---- epilogue: LSTM cell, state update (fold next-step mask), outputs ----
  const int hcol = ht * 32 + ch * 16 + (l & 15);
  const float bi = bias[hcol], bf2 = bias[512 + hcol];
  const float bg = bias[1024 + hcol], bo = bias[1536 + hcol];
  float* Hl = (float*)smem;            // [64][36] f32 (pad 36 for bank spread)
  float* Cl = (float*)(smem + 9216);   // [64][36] f32
  const int cfi = ht * 2 + ch;
  const int colL = ch * 16 + (l & 15);
  #pragma unroll
  for (int mb2 = 0; mb2 < 2; ++mb2) {
    const int mb_abs = mt * 4 + mh * 2 + mb2;
    const int fid = mb_abs * 32 + cfi;
    f32x4 cold = *(const f32x4*)(cf + (size_t)fid * 256u + l * 4u);
    f32x4 cmask;
    #pragma unroll
    for (int r = 0; r < 4; ++r) {
      float gi = sigm(acc[mb2][0][r] + bi);
      float gf = sigm(acc[mb2][1][r] + bf2);
      float gg = tanhf(acc[mb2][2][r] + bg);
      float go = sigm(acc[mb2][3][r] + bo);
      float c = gf * cold[r] + gi * gg;
      float h = go * tanhf(c);
      int brow = mb_abs * 16 + ((l >> 4) << 2) + r;
      float keep = 1.0f - dones[brow * 64 + t];   // next step's mask (fold-in)
      cmask[r] = c * keep;
      int rowL = mh * 32 + mb2 * 16 + ((l >> 4) << 2) + r;
      Hl[rowL * 36 + colL] = h;
      Cl[rowL * 36 + colL] = c;
    }
    *(f32x4*)(cf + (size_t)fid * 256u + l * 4u) = cmask;
  }
  __syncthreads();

  // (a) repack h (masked) into frag-major bf16 state for next step's A operand
  {
    const int mb2f = tid >> 6, lp = tid & 63;
    const int mb_abs = mt * 4 + mb2f;
    const int rowL = mb2f * 16 + (lp & 15);
    const int c0 = (lp >> 4) << 3;
    const int brow = mt * 64 + rowL;
    const float keep = 1.0f - dones[brow * 64 + t];
    const float* hr = Hl + rowL * 36 + c0;
    u32x4 p;
    p.x = pack2(hr[0] * keep, hr[1] * keep);
    p.y = pack2(hr[2] * keep, hr[3] * keep);
    p.z = pack2(hr[4] * keep, hr[5] * keep);
    p.w = pack2(hr[6] * keep, hr[7] * keep);
    *(u32x4*)(hf + ((size_t)(mb_abs * 16 + ht) * 64u + lp) * 8u) = p;
  }
  // (b) coalesced f32 outputs: x, h_stack, c_stack (+ rnn_states at t=63)
  {
    const int row = tid & 63, cg = tid >> 6;
    const int b = mt * 64 + row;
    const int c0 = cg * 8;
    const float* hr = Hl + row * 36 + c0;
    const float* cr = Cl + row * 36 + c0;
    f32x4 h0 = *(const f32x4*)hr,  h1 = *(const f32x4*)(hr + 4);
    f32x4 cc0 = *(const f32x4*)cr, cc1 = *(const f32x4*)(cr + 4);
    const int colg = ht * 32 + c0;
    size_t xoff = ((size_t)(b * 64 + t)) * 512u + colg;
    *(f32x4*)(out + xoff) = h0; *(f32x4*)(out + xoff + 4) = h1;
    size_t hoff = OUT_HS + ((size_t)(t * 1024 + b)) * 512u + colg;
    *(f32x4*)(out + hoff) = h0; *(f32x4*)(out + hoff + 4) = h1;
    size_t coff = OUT_CS + ((size_t)(t * 1024 + b)) * 512u + colg;
    *(f32x4*)(out + coff) = cc0; *(f32x4*)(out + coff + 4) = cc1;
    if (t == 63) {
      size_t roff = OUT_RNN + (size_t)b * 1024u + colg;
      *(f32x4*)(out + roff) = h0;        *(f32x4*)(out + roff + 4) = h1;
      *(f32x4*)(out + roff + 512) = cc0; *(f32x4*)(out + roff + 516) = cc1;
    }
  }
}

extern "C" void kernel_launch(void* const* d_in, const int* in_sizes, int n_in,
                              void* d_out, int out_size, void* d_ws, size_t ws_size,
                              hipStream_t stream) {
  const float* xg  = (const float*)d_in[0];
  const float* rnn = (const float*)d_in[1];
  const float* dn  = (const float*)d_in[2];
  const float* Wih = (const float*)d_in[3];
  const float* Whh = (const float*)d_in[4];
  const float* bih = (const float*)d_in[5];
  const float* bhh = (const float*)d_in[6];
  float* out = (float*)d_out;
  unsigned char* ws = (unsigned char*)d_ws;
  (void)in_sizes; (void)n_in; (void)out_size; (void)ws_size;

  prep_kernel<<<1800, 256, 0, stream>>>(rnn, Wih, Whh, bih, bhh, ws);
  for (int t = 0; t < 64; ++t)
    step_kernel<<<256, 256, 0, stream>>>(xg, dn, ws, out, t);
}

// Round 2
// 1142.755 us; speedup vs baseline: 1.3641x; 1.3641x over previous
//
#include <hip/hip_runtime.h>
#include <stdint.h>

// PolicyCoreRNN: LSTM, B=1024, T=64, H=I=512.
// Round 2: hoist x @ W_ih^T + bias into ONE big GEMM (no sequential dep),
// stored bf16 in MFMA-D-fragment layout (256 MiB in ws). Sequential part is
// then only h @ W_hh^T (K=512): 64 step kernels, 8 K-iters each.
// Falls back to the round-1 fused-K path if ws_size is too small.

// ---------- round-1 (fallback) ws layout ----------
#define WC_OFF   0u
#define HF_OFF   4194304u
#define CF_OFF   5242880u
#define BIAS_OFF 7340032u
// ---------- fast-path ws layout (bytes) ----------
#define F_WIH   0u           // 2 MiB  bf16 W_ih frags (cb*16+ks)*1024, ks<16
#define F_WHH   2097152u     // 2 MiB  bf16 W_hh frags
#define F_HF    4194304u     // 1 MiB  bf16 h-state frags (mb*16+ks)*1024
#define F_CF    5242880u     // 2 MiB  f32 c-state D-frags (mb*32+cfi)*1024
#define F_BIAS  7340032u     // 8 KiB  f32 b_ih+b_hh
#define F_XBF   8388608u     // 64 MiB bf16 x frags ((t*64+mb)*16+ks)*1024
#define F_XPROJ 75497472u    // 256 MiB bf16 x_proj D-frags ((t*64+mb)*128+n)*512
#define F_NEED  343932928u
// out (f32 elements): x | new_rnn_states | h_stack | c_stack
#define OUT_RNN  33554432u
#define OUT_HS   34603008u
#define OUT_CS   68157440u

typedef __attribute__((ext_vector_type(4))) float f32x4;
typedef __attribute__((ext_vector_type(8))) short s16x8;
typedef __attribute__((ext_vector_type(4))) unsigned int u32x4;
typedef __attribute__((ext_vector_type(4))) unsigned short u16x4;

__device__ __forceinline__ unsigned short f2bf(float f) {
  union { float f; unsigned int u; } v; v.f = f;
  return (unsigned short)((v.u + 0x7FFFu + ((v.u >> 16) & 1u)) >> 16);
}
__device__ __forceinline__ float bf2f(unsigned short s) {
  union { unsigned int u; float f; } v; v.u = ((unsigned int)s) << 16;
  return v.f;
}
__device__ __forceinline__ unsigned int pack2(float a, float b) {
  return (unsigned int)f2bf(a) | ((unsigned int)f2bf(b) << 16);
}
__device__ __forceinline__ float sigm(float x) { return 1.0f / (1.0f + __expf(-x)); }

__device__ __forceinline__ void gl_lds16(const void* g, void* lds) {
  __builtin_amdgcn_global_load_lds(
      (const __attribute__((address_space(1))) unsigned int*)g,
      (__attribute__((address_space(3))) unsigned int*)lds, 16, 0, 0);
}

// Fragment conventions (16x16x32 bf16 MFMA):
//  A/B input frag (1KB): lane l holds index (l&15) of the 16-dim, k = ks*32+(l>>4)*8+e.
//  D frag: col = l&15 (B dim), row = (l>>4)*4 + reg (A dim).  [m89-verified]

// ====================== FAST PATH ======================

__global__ void __launch_bounds__(256) prep_fast(
    const float* __restrict__ xg, const float* __restrict__ rnn,
    const float* __restrict__ Wih, const float* __restrict__ Whh,
    const float* __restrict__ bih, const float* __restrict__ bhh,
    unsigned char* __restrict__ ws) {
  unsigned int tid = blockIdx.x * 256u + threadIdx.x;
  unsigned short* wih_f = (unsigned short*)(ws + F_WIH);
  unsigned short* whh_f = (unsigned short*)(ws + F_WHH);
  unsigned short* hf    = (unsigned short*)(ws + F_HF);
  float* cf   = (float*)(ws + F_CF);
  float* bias = (float*)(ws + F_BIAS);
  unsigned short* xbf = (unsigned short*)(ws + F_XBF);
  if (tid < 131072u) {
    // W_ih frags: frag=(cb<128, ks<16); col=cb*16+(l&15); k0=ks*32+(l>>4)*8
    unsigned int frag = tid >> 6, l = tid & 63u;
    unsigned int cb = frag >> 4, ks = frag & 15u;
    unsigned int g  = cb * 16u + (l & 15u);
    unsigned int k0 = ks * 32u + ((l >> 4) << 3);
    const float* src = Wih + (size_t)g * 512u + k0;
    u32x4 p;
    p.x = pack2(src[0], src[1]); p.y = pack2(src[2], src[3]);
    p.z = pack2(src[4], src[5]); p.w = pack2(src[6], src[7]);
    *(u32x4*)(wih_f + (size_t)frag * 512u + l * 8u) = p;
  } else if (tid < 262144u) {
    unsigned int t2 = tid - 131072u;
    unsigned int frag = t2 >> 6, l = t2 & 63u;
    unsigned int cb = frag >> 4, ks = frag & 15u;
    unsigned int g  = cb * 16u + (l & 15u);
    unsigned int k0 = ks * 32u + ((l >> 4) << 3);
    const float* src = Whh + (size_t)g * 512u + k0;
    u32x4 p;
    p.x = pack2(src[0], src[1]); p.y = pack2(src[2], src[3]);
    p.z = pack2(src[4], src[5]); p.w = pack2(src[6], src[7]);
    *(u32x4*)(whh_f + (size_t)frag * 512u + l * 8u) = p;
  } else if (tid < 327680u) {
    // h0 frags: frag=(mb<64, ks<16); b=mb*16+(l&15); hcol0=ks*32+(l>>4)*8
    unsigned int t2 = tid - 262144u;
    unsigned int frag = t2 >> 6, l = t2 & 63u;
    unsigned int mb = frag >> 4, ks = frag & 15u;
    unsigned int b  = mb * 16u + (l & 15u);
    unsigned int c0 = ks * 32u + ((l >> 4) << 3);
    const float* src = rnn + (size_t)b * 1024u + c0;
    u32x4 p;
    p.x = pack2(src[0], src[1]); p.y = pack2(src[2], src[3]);
    p.z = pack2(src[4], src[5]); p.w = pack2(src[6], src[7]);
    *(u32x4*)(hf + (size_t)frag * 512u + l * 8u) = p;
  } else if (tid < 458752u) {
    // c0 D-frags: frag=(mb<64, cfi<32); b=mb*16+(l>>4)*4+r; hcol=cfi*16+(l&15)
    unsigned int t2 = tid - 327680u;
    unsigned int frag = t2 >> 6, l = t2 & 63u;
    unsigned int mb = frag >> 5, cfi = frag & 31u;
    unsigned int hcol = cfi * 16u + (l & 15u);
    f32x4 p;
    #pragma unroll
    for (int r = 0; r < 4; ++r) {
      unsigned int b = mb * 16u + ((l >> 4) << 2) + r;
      p[r] = rnn[(size_t)b * 1024u + 512u + hcol];
    }
    *(f32x4*)(cf + (size_t)frag * 256u + l * 4u) = p;
  } else if (tid < 460800u) {
    unsigned int g = tid - 458752u;
    bias[g] = bih[g] + bhh[g];
  } else if (tid < 4655104u) {
    // x frags: frag=(t<64, mb<64, ks<16); b=mb*16+(l&15); k0=ks*32+(l>>4)*8
    unsigned int t2 = tid - 460800u;
    unsigned int frag = t2 >> 6, l = t2 & 63u;
    unsigned int ks = frag & 15u, mb = (frag >> 4) & 63u, t = frag >> 10;
    unsigned int b  = mb * 16u + (l & 15u);
    unsigned int k0 = ks * 32u + ((l >> 4) << 3);
    const float* src = xg + ((size_t)(b * 64u + t)) * 512u + k0;
    u32x4 p;
    p.x = pack2(src[0], src[1]); p.y = pack2(src[2], src[3]);
    p.z = pack2(src[4], src[5]); p.w = pack2(src[6], src[7]);
    *(u32x4*)(xbf + (size_t)frag * 512u + l * 8u) = p;
  }
}

// Big GEMM: x_proj[t] = x_t @ W_ih^T + bias, bf16 D-frag output.
// grid 8192 = t(64) x mtile(8) x ntile(16); tile 128M x 128N, K=512, BK=64.
__global__ void __launch_bounds__(256) gemm_xproj(unsigned char* __restrict__ ws) {
  const unsigned short* xbf = (const unsigned short*)(ws + F_XBF);
  const unsigned short* wih = (const unsigned short*)(ws + F_WIH);
  const float* bias = (const float*)(ws + F_BIAS);
  unsigned short* xproj = (unsigned short*)(ws + F_XPROJ);

  __shared__ __align__(16) unsigned char smem[65536];
  const int tid = threadIdx.x;
  const int w = tid >> 6, l = tid & 63;
  const int mh = w & 1, nh = w >> 1;
  const int bid = blockIdx.x;
  const int t = bid >> 7, mtile = (bid >> 4) & 7, ntile = bid & 15;

  f32x4 acc[4][4];
  {
    f32x4 z = {0.f, 0.f, 0.f, 0.f};
    #pragma unroll
    for (int i = 0; i < 4; ++i)
      #pragma unroll
      for (int j = 0; j < 4; ++j) acc[i][j] = z;
  }

  auto stage = [&](int kc, int buf) {
    unsigned char* ab = smem + buf * 16384;
    unsigned char* bb = smem + 32768 + buf * 16384;
    #pragma unroll
    for (int j = 0; j < 4; ++j) {   // A: 16 frags
      int idx = w * 4 + j;
      int mb_l = idx >> 1, ksl = idx & 1;
      size_t frag = (size_t)(t * 64 + mtile * 8 + mb_l) * 16u + kc * 2 + ksl;
      gl_lds16(xbf + (frag * 64u + l) * 8u, ab + idx * 1024);
    }
    #pragma unroll
    for (int j = 0; j < 4; ++j) {   // B: 16 frags
      int idx = w * 4 + j;
      int cb_l = idx >> 1, ksl = idx & 1;
      size_t frag = (size_t)(ntile * 8 + cb_l) * 16u + kc * 2 + ksl;
      gl_lds16(wih + (frag * 64u + l) * 8u, bb + idx * 1024);
    }
  };

  stage(0, 0);
  __syncthreads();
  for (int kc = 0; kc < 8; ++kc) {
    int cur = kc & 1;
    if (kc < 7) stage(kc + 1, cur ^ 1);
    unsigned char* ab = smem + cur * 16384;
    unsigned char* bb = smem + 32768 + cur * 16384;
    s16x8 afr[4][2], bfr[4][2];
    #pragma unroll
    for (int m = 0; m < 4; ++m)
      #pragma unroll
      for (int ksl = 0; ksl < 2; ++ksl)
        afr[m][ksl] = *(const s16x8*)(ab + ((mh * 4 + m) * 2 + ksl) * 1024 + l * 16);
    #pragma unroll
    for (int n = 0; n < 4; ++n)
      #pragma unroll
      for (int ksl = 0; ksl < 2; ++ksl)
        bfr[n][ksl] = *(const s16x8*)(bb + ((nh * 4 + n) * 2 + ksl) * 1024 + l * 16);
    #pragma unroll
    for (int m = 0; m < 4; ++m)
      #pragma unroll
      for (int n = 0; n < 4; ++n)
        #pragma unroll
        for (int ksl = 0; ksl < 2; ++ksl)
          acc[m][n] = __builtin_amdgcn_mfma_f32_16x16x32_bf16(
              afr[m][ksl], bfr[n][ksl], acc[m][n], 0, 0, 0);
    __syncthreads();
  }

  #pragma unroll
  for (int m = 0; m < 4; ++m) {
    int mb_abs = mtile * 8 + mh * 4 + m;
    #pragma unroll
    for (int n = 0; n < 4; ++n) {
      int n_abs = ntile * 8 + nh * 4 + n;
      float bc = bias[n_abs * 16 + (l & 15)];
      u16x4 p;
      #pragma unroll
      for (int r = 0; r < 4; ++r) p[r] = f2bf(acc[m][n][r] + bc);
      *(u16x4*)(xproj + ((size_t)(t * 64 + mb_abs) * 128u + n_abs) * 256u + l * 4u) = p;
    }
  }
}

// Step: gates = x_proj[t] + h @ W_hh^T (K=512). grid 256 = mt(16) x ht(16).
__global__ void __launch_bounds__(256) step_fast(
    const float* __restrict__ dones, unsigned char* __restrict__ ws,
    float* __restrict__ out, int t) {
  const unsigned short* whh = (const unsigned short*)(ws + F_WHH);
  unsigned short* hf = (unsigned short*)(ws + F_HF);
  float* cf = (float*)(ws + F_CF);
  const unsigned short* xproj = (const unsigned short*)(ws + F_XPROJ);

  __shared__ __align__(16) unsigned char smem[49152];
  const int tid = threadIdx.x;
  const int w = tid >> 6, l = tid & 63;
  const int mh = w & 1, ch = w >> 1;
  const int mt = (int)blockIdx.x >> 4, ht = (int)blockIdx.x & 15;

  f32x4 acc[2][4];
  {
    f32x4 z = {0.f, 0.f, 0.f, 0.f};
    #pragma unroll
    for (int i = 0; i < 2; ++i)
      #pragma unroll
      for (int j = 0; j < 4; ++j) acc[i][j] = z;
  }

  auto stage = [&](int kc, int buf) {
    unsigned char* bb = smem + 16384 + buf * 16384;
    #pragma unroll
    for (int j = 0; j < 4; ++j) {   // B: 16 frags (4 gates x 2 cb x 2 ks)
      int idx = w * 4 + j;
      int g = idx >> 2, cbl = (idx >> 1) & 1, ksl = idx & 1;
      int cb = g * 32 + ht * 2 + cbl;
      int ks = kc * 2 + ksl;
      gl_lds16(whh + ((size_t)(cb * 16 + ks) * 64u + l) * 8u, bb + idx * 1024);
    }
    unsigned char* ab = smem + buf * 8192;
    #pragma unroll
    for (int j = 0; j < 2; ++j) {   // A: 8 frags (4 mb x 2 ks)
      int idx = w * 2 + j;
      int mb_l = idx >> 1, ksl = idx & 1;
      int frag = (mt * 4 + mb_l) * 16 + kc * 2 + ksl;
      gl_lds16(hf + ((size_t)frag * 64u + l) * 8u, ab + idx * 1024);
    }
  };

  stage(0, 0);
  __syncthreads();
  for (int kc = 0; kc < 8; ++kc) {
    int cur = kc & 1;
    if (kc < 7) stage(kc + 1, cur ^ 1);
    unsigned char* ab = smem + cur * 8192;
    unsigned char* bb = smem + 16384 + cur * 16384;
    s16x8 afr[2][2], bfr[4][2];
    #pragma unroll
    for (int mb2 = 0; mb2 < 2; ++mb2)
      #pragma unroll
      for (int ksl = 0; ksl < 2; ++ksl)
        afr[mb2][ksl] = *(const s16x8*)(ab + ((mh * 2 + mb2) * 2 + ksl) * 1024 + l * 16);
    #pragma unroll
    for (int g = 0; g < 4; ++g)
      #pragma unroll
      for (int ksl = 0; ksl < 2; ++ksl)
        bfr[g][ksl] = *(const s16x8*)(bb + (g * 4 + ch * 2 + ksl) * 1024 + l * 16);
    #pragma unroll
    for (int mb2 = 0; mb2 < 2; ++mb2)
      #pragma unroll
      for (int g = 0; g < 4; ++g)
        #pragma unroll
        for (int ksl = 0; ksl < 2; ++ksl)
          acc[mb2][g] = __builtin_amdgcn_mfma_f32_16x16x32_bf16(
              afr[mb2][ksl], bfr[g][ksl], acc[mb2][g], 0, 0, 0);
    __syncthreads();
  }

  // add x_proj (bf16 D-frags, bias already folded in)
  #pragma unroll
  for (int mb2 = 0; mb2 < 2; ++mb2) {
    int mb_abs = mt * 4 + mh * 2 + mb2;
    #pragma unroll
    for (int g = 0; g < 4; ++g) {
      int n_abs = g * 32 + ht * 2 + ch;
      u16x4 xpv = *(const u16x4*)(xproj + ((size_t)(t * 64 + mb_abs) * 128u + n_abs) * 256u + l * 4u);
      #pragma unroll
      for (int r = 0; r < 4; ++r) acc[mb2][g][r] += bf2f(xpv[r]);
    }
  }

  // ---- LSTM cell, state update (fold next-step mask), outputs ----
  float* Hl = (float*)smem;            // [64][36] f32
  float* Cl = (float*)(smem + 9216);   // [64][36] f32
  const int cfi = ht * 2 + ch;
  const int colL = ch * 16 + (l & 15);
  #pragma unroll
  for (int mb2 = 0; mb2 < 2; ++mb2) {
    const int mb_abs = mt * 4 + mh * 2 + mb2;
    const int fid = mb_abs * 32 + cfi;
    f32x4 cold = *(const f32x4*)(cf + (size_t)fid * 256u + l * 4u);
    f32x4 cmask;
    #pragma unroll
    for (int r = 0; r < 4; ++r) {
      float gi = sigm(acc[mb2][0][r]);
      float gf = sigm(acc[mb2][1][r]);
      float gg = tanhf(acc[mb2][2][r]);
      float go = sigm(acc[mb2][3][r]);
      float c = gf * cold[r] + gi * gg;
      float h = go * tanhf(c);
      int brow = mb_abs * 16 + ((l >> 4) << 2) + r;
      float keep = 1.0f - dones[brow * 64 + t];   // next step's mask fold-in
      cmask[r] = c * keep;
      int rowL = mh * 32 + mb2 * 16 + ((l >> 4) << 2) + r;
      Hl[rowL * 36 + colL] = h;
      Cl[rowL * 36 + colL] = c;
    }
    *(f32x4*)(cf + (size_t)fid * 256u + l * 4u) = cmask;
  }
  __syncthreads();

  {  // repack masked h into frag-major bf16 state (next step's A)
    const int mb2f = tid >> 6, lp = tid & 63;
    const int mb_abs = mt * 4 + mb2f;
    const int rowL = mb2f * 16 + (lp & 15);
    const int c0 = (lp >> 4) << 3;
    const int brow = mt * 64 + rowL;
    const float keep = 1.0f - dones[brow * 64 + t];
    const float* hr = Hl + rowL * 36 + c0;
    u32x4 p;
    p.x = pack2(hr[0] * keep, hr[1] * keep);
    p.y = pack2(hr[2] * keep, hr[3] * keep);
    p.z = pack2(hr[4] * keep, hr[5] * keep);
    p.w = pack2(hr[6] * keep, hr[7] * keep);
    *(u32x4*)(hf + ((size_t)(mb_abs * 16 + ht) * 64u + lp) * 8u) = p;
  }
  {  // coalesced f32 outputs
    const int row = tid & 63, cg = tid >> 6;
    const int b = mt * 64 + row;
    const int c0 = cg * 8;
    const float* hr = Hl + row * 36 + c0;
    const float* cr = Cl + row * 36 + c0;
    f32x4 h0 = *(const f32x4*)hr,  h1 = *(const f32x4*)(hr + 4);
    f32x4 cc0 = *(const f32x4*)cr, cc1 = *(const f32x4*)(cr + 4);
    const int colg = ht * 32 + c0;
    size_t xoff = ((size_t)(b * 64 + t)) * 512u + colg;
    *(f32x4*)(out + xoff) = h0; *(f32x4*)(out + xoff + 4) = h1;
    size_t hoff = OUT_HS + ((size_t)(t * 1024 + b)) * 512u + colg;
    *(f32x4*)(out + hoff) = h0; *(f32x4*)(out + hoff + 4) = h1;
    size_t coff = OUT_CS + ((size_t)(t * 1024 + b)) * 512u + colg;
    *(f32x4*)(out + coff) = cc0; *(f32x4*)(out + coff + 4) = cc1;
    if (t == 63) {
      size_t roff = OUT_RNN + (size_t)b * 1024u + colg;
      *(f32x4*)(out + roff) = h0;        *(f32x4*)(out + roff + 4) = h1;
      *(f32x4*)(out + roff + 512) = cc0; *(f32x4*)(out + roff + 516) = cc1;
    }
  }
}

// ====================== FALLBACK (round-1, verified) ======================

__global__ void __launch_bounds__(256) prep_kernel(
    const float* __restrict__ rnn, const float* __restrict__ Wih,
    const float* __restrict__ Whh, const float* __restrict__ bih,
    const float* __restrict__ bhh, unsigned char* __restrict__ ws) {
  unsigned int tid = blockIdx.x * 256u + threadIdx.x;
  unsigned short* wcf = (unsigned short*)(ws + WC_OFF);
  unsigned short* hf  = (unsigned short*)(ws + HF_OFF);
  float* cf   = (float*)(ws + CF_OFF);
  float* bias = (float*)(ws + BIAS_OFF);
  if (tid < 262144u) {
    unsigned int frag = tid >> 6, l = tid & 63u;
    unsigned int cb = frag >> 5, ks = frag & 31u;
    unsigned int g  = cb * 16u + (l & 15u);
    unsigned int k0 = ks * 32u + ((l >> 4) << 3);
    const float* src = (k0 < 512u) ? (Wih + g * 512u + k0) : (Whh + g * 512u + (k0 - 512u));
    u32x4 p;
    p.x = pack2(src[0], src[1]); p.y = pack2(src[2], src[3]);
    p.z = pack2(src[4], src[5]); p.w = pack2(src[6], src[7]);
    *(u32x4*)(wcf + (size_t)frag * 512u + l * 8u) = p;
  } else if (tid < 327680u) {
    unsigned int t2 = tid - 262144u;
    unsigned int frag = t2 >> 6, l = t2 & 63u;
    unsigned int mb = frag >> 4, ks = frag & 15u;
    unsigned int b  = mb * 16u + (l & 15u);
    unsigned int c0 = ks * 32u + ((l >> 4) << 3);
    const float* src = rnn + (size_t)b * 1024u + c0;
    u32x4 p;
    p.x = pack2(src[0], src[1]); p.y = pack2(src[2], src[3]);
    p.z = pack2(src[4], src[5]); p.w = pack2(src[6], src[7]);
    *(u32x4*)(hf + (size_t)frag * 512u + l * 8u) = p;
  } else if (tid < 458752u) {
    unsigned int t2 = tid - 327680u;
    unsigned int frag = t2 >> 6, l = t2 & 63u;
    unsigned int mb = frag >> 5, cfi = frag & 31u;
    unsigned int hcol = cfi * 16u + (l & 15u);
    f32x4 p;
    #pragma unroll
    for (int r = 0; r < 4; ++r) {
      unsigned int b = mb * 16u + ((l >> 4) << 2) + r;
      p[r] = rnn[(size_t)b * 1024u + 512u + hcol];
    }
    *(f32x4*)(cf + (size_t)frag * 256u + l * 4u) = p;
  } else if (tid < 460800u) {
    unsigned int g = tid - 458752u;
    bias[g] = bih[g] + bhh[g];
  }
}

__global__ void __launch_bounds__(256) step_kernel(
    const float* __restrict__ xg, const float* __restrict__ dones,
    unsigned char* __restrict__ ws, float* __restrict__ out, int t) {
  const unsigned short* wcf = (const unsigned short*)(ws + WC_OFF);
  unsigned short* hf = (unsigned short*)(ws + HF_OFF);
  float* cf = (float*)(ws + CF_OFF);
  const float* bias = (const float*)(ws + BIAS_OFF);

  __shared__ __align__(16) unsigned char smem[49152];
  const int tid = threadIdx.x;
  const int w = tid >> 6, l = tid & 63;
  const int mh = w & 1, ch = w >> 1;
  const int mt = (int)blockIdx.x >> 4, ht = (int)blockIdx.x & 15;

  f32x4 acc[2][4];
  {
    f32x4 z = {0.f, 0.f, 0.f, 0.f};
    #pragma unroll
    for (int i = 0; i < 2; ++i)
      #pragma unroll
      for (int j = 0; j < 4; ++j) acc[i][j] = z;
  }

  f32x4 xv[2][2];

  auto stage_load = [&](int kc, int buf) {
    unsigned char* bb = smem + 16384 + buf * 16384;
    #pragma unroll
    for (int j = 0; j < 4; ++j) {
      int idx = w * 4 + j;
      int g = idx >> 2, cbl = (idx >> 1) & 1, ksl = idx & 1;
      int cb = g * 32 + ht * 2 + cbl;
      int ks = kc * 2 + ksl;
      const unsigned short* src = wcf + ((size_t)(cb * 32 + ks) * 64u + l) * 8u;
      gl_lds16(src, bb + idx * 1024);
    }
    unsigned char* ab = smem + buf * 8192;
    if (kc >= 8) {
      #pragma unroll
      for (int j = 0; j < 2; ++j) {
        int idx = w * 2 + j;
        int ksh = (kc - 8) * 2 + j;
        int mb_abs = mt * 4 + w;
        const unsigned short* src = hf + ((size_t)(mb_abs * 16 + ksh) * 64u + l) * 8u;
        gl_lds16(src, ab + idx * 1024);
      }
    } else {
      #pragma unroll
      for (int j = 0; j < 2; ++j) {
        int ks = kc * 2 + j;
        int b = mt * 64 + w * 16 + (l & 15);
        int k0 = ks * 32 + ((l >> 4) << 3);
        const float* src = xg + ((size_t)(b * 64 + t)) * 512u + k0;
        xv[j][0] = *(const f32x4*)src;
        xv[j][1] = *(const f32x4*)(src + 4);
      }
    }
  };
  auto stage_write = [&](int kc, int buf) {
    if (kc < 8) {
      unsigned char* ab = smem + buf * 8192;
      #pragma unroll
      for (int j = 0; j < 2; ++j) {
        int idx = w * 2 + j;
        u32x4 p;
        p.x = pack2(xv[j][0].x, xv[j][0].y); p.y = pack2(xv[j][0].z, xv[j][0].w);
        p.z = pack2(xv[j][1].x, xv[j][1].y); p.w = pack2(xv[j][1].z, xv[j][1].w);
        *(u32x4*)(ab + idx * 1024 + l * 16) = p;
      }
    }
  };

  stage_load(0, 0);
  stage_write(0, 0);
  __syncthreads();

  for (int kc = 0; kc < 16; ++kc) {
    int cur = kc & 1;
    if (kc < 15) stage_load(kc + 1, cur ^ 1);
    unsigned char* ab = smem + cur * 8192;
    unsigned char* bb = smem + 16384 + cur * 16384;
    s16x8 afr[2][2], bfr[4][2];
    #pragma unroll
    for (int mb2 = 0; mb2 < 2; ++mb2)
      #pragma unroll
      for (int ksl = 0; ksl < 2; ++ksl)
        afr[mb2][ksl] = *(const s16x8*)(ab + ((mh * 2 + mb2) * 2 + ksl) * 1024 + l * 16);
    #pragma unroll
    for (int g = 0; g < 4; ++g)
      #pragma unroll
      for (int ksl = 0; ksl < 2; ++ksl)
        bfr[g][ksl] = *(const s16x8*)(bb + (g * 4 + ch * 2 + ksl) * 1024 + l * 16);
    #pragma unroll
    for (int mb2 = 0; mb2 < 2; ++mb2)
      #pragma unroll
      for (int g = 0; g < 4; ++g)
        #pragma unroll
        for (int ksl = 0; ksl < 2; ++ksl)
          acc[mb2][g] = __builtin_amdgcn_mfma_f32_16x16x32_bf16(
              afr[mb2][ksl], bfr[g][ksl], acc[mb2][g], 0, 0, 0);
    if (kc < 15) stage_write(kc + 1, cur ^ 1);
    __syncthreads();
  }

  const int hcol = ht * 32 + ch * 16 + (l & 15);
  const float bi = bias[hcol], bf2 = bias[512 + hcol];
  const float bg = bias[1024 + hcol], bo = bias[1536 + hcol];
  float* Hl = (float*)smem;
  float* Cl = (float*)(smem + 9216);
  const int cfi = ht * 2 + ch;
  const int colL = ch * 16 + (l & 15);
  #pragma unroll
  for (int mb2 = 0; mb2 < 2; ++mb2) {
    const int mb_abs = mt * 4 + mh * 2 + mb2;
    const int fid = mb_abs * 32 + cfi;
    f32x4 cold = *(const f32x4*)(cf + (size_t)fid * 256u + l * 4u);
    f32x4 cmask;
    #pragma unroll
    for (int r = 0; r < 4; ++r) {
      float gi = sigm(acc[mb2][0][r] + bi);
      float gf = sigm(acc[mb2][1][r] + bf2);
      float gg = tanhf(acc[mb2][2][r] + bg);
      float go = sigm(acc[mb2][3][r] + bo);
      float c = gf * cold[r] + gi * gg;
      float h = go * tanhf(c);
      int brow = mb_abs * 16 + ((l >> 4) << 2) + r;
      float keep = 1.0f - dones[brow * 64 + t];
      cmask[r] = c * keep;
      int rowL = mh * 32 + mb2 * 16 + ((l >> 4) << 2) + r;
      Hl[rowL * 36 + colL] = h;
      Cl[rowL * 36 + colL] = c;
    }
    *(f32x4*)(cf + (size_t)fid * 256u + l * 4u) = cmask;
  }
  __syncthreads();

  {
    const int mb2f = tid >> 6, lp = tid & 63;
    const int mb_abs = mt * 4 + mb2f;
    const int rowL = mb2f * 16 + (lp & 15);
    const int c0 = (lp >> 4) << 3;
    const int brow = mt * 64 + rowL;
    const float keep = 1.0f - dones[brow * 64 + t];
    const float* hr = Hl + rowL * 36 + c0;
    u32x4 p;
    p.x = pack2(hr[0] * keep, hr[1] * keep);
    p.y = pack2(hr[2] * keep, hr[3] * keep);
    p.z = pack2(hr[4] * keep, hr[5] * keep);
    p.w = pack2(hr[6] * keep, hr[7] * keep);
    *(u32x4*)(hf + ((size_t)(mb_abs * 16 + ht) * 64u + lp) * 8u) = p;
  }
  {
    const int row = tid & 63, cg = tid >> 6;
    const int b = mt * 64 + row;
    const int c0 = cg * 8;
    const float* hr = Hl + row * 36 + c0;
    const float* cr = Cl + row * 36 + c0;
    f32x4 h0 = *(const f32x4*)hr,  h1 = *(const f32x4*)(hr + 4);
    f32x4 cc0 = *(const f32x4*)cr, cc1 = *(const f32x4*)(cr + 4);
    const int colg = ht * 32 + c0;
    size_t xoff = ((size_t)(b * 64 + t)) * 512u + colg;
    *(f32x4*)(out + xoff) = h0; *(f32x4*)(out + xoff + 4) = h1;
    size_t hoff = OUT_HS + ((size_t)(t * 1024 + b)) * 512u + colg;
    *(f32x4*)(out + hoff) = h0; *(f32x4*)(out + hoff + 4) = h1;
    size_t coff = OUT_CS + ((size_t)(t * 1024 + b)) * 512u + colg;
    *(f32x4*)(out + coff) = cc0; *(f32x4*)(out + coff + 4) = cc1;
    if (t == 63) {
      size_t roff = OUT_RNN + (size_t)b * 1024u + colg;
      *(f32x4*)(out + roff) = h0;        *(f32x4*)(out + roff + 4) = h1;
      *(f32x4*)(out + roff + 512) = cc0; *(f32x4*)(out + roff + 516) = cc1;
    }
  }
}

extern "C" void kernel_launch(void* const* d_in, const int* in_sizes, int n_in,
                              void* d_out, int out_size, void* d_ws, size_t ws_size,
                              hipStream_t stream) {
  const float* xg  = (const float*)d_in[0];
  const float* rnn = (const float*)d_in[1];
  const float* dn  = (const float*)d_in[2];
  const float* Wih = (const float*)d_in[3];
  const float* Whh = (const float*)d_in[4];
  const float* bih = (const float*)d_in[5];
  const float* bhh = (const float*)d_in[6];
  float* out = (float*)d_out;
  unsigned char* ws = (unsigned char*)d_ws;
  (void)in_sizes; (void)n_in; (void)out_size;

  if (ws_size >= (size_t)F_NEED) {
    prep_fast<<<18184, 256, 0, stream>>>(xg, rnn, Wih, Whh, bih, bhh, ws);
    gemm_xproj<<<8192, 256, 0, stream>>>(ws);
    for (int t = 0; t < 64; ++t)
      step_fast<<<256, 256, 0, stream>>>(dn, ws, out, t);
  } else {
    prep_kernel<<<1800, 256, 0, stream>>>(rnn, Wih, Whh, bih, bhh, ws);
    for (int t = 0; t < 64; ++t)
      step_kernel<<<256, 256, 0, stream>>>(xg, dn, ws, out, t);
  }
}

// Round 3
// 1029.604 us; speedup vs baseline: 1.5140x; 1.1099x over previous
//
#include <hip/hip_runtime.h>
#include <stdint.h>

// PolicyCoreRNN: LSTM, B=1024, T=64, H=I=512.
// Round 3: barrier-free step main loop. W_hh tile (128KB) staged to LDS once,
// h-operand (A) loaded straight to VGPRs, ONE __syncthreads, then 8 unrolled
// K-iterations of ds_read+MFMA with no barriers/drains. xproj/c/dones
// preloaded to hide latency. prep/gemm_xproj unchanged from round 2.

// ---------- round-1 (fallback) ws layout ----------
#define WC_OFF   0u
#define HF_OFF   4194304u
#define CF_OFF   5242880u
#define BIAS_OFF 7340032u
// ---------- fast-path ws layout (bytes) ----------
#define F_WIH   0u           // 2 MiB  bf16 W_ih frags (cb*16+ks)*1024
#define F_WHH   2097152u     // 2 MiB  bf16 W_hh frags
#define F_HF    4194304u     // 1 MiB  bf16 h-state frags (mb*16+ks)*1024
#define F_CF    5242880u     // 2 MiB  f32 c-state D-frags (mb*32+cfi)*1024
#define F_BIAS  7340032u     // 8 KiB  f32 b_ih+b_hh
#define F_XBF   8388608u     // 64 MiB bf16 x frags ((t*64+mb)*16+ks)*1024
#define F_XPROJ 75497472u    // 256 MiB bf16 x_proj D-frags ((t*64+mb)*128+n)*512
#define F_NEED  343932928u
// out (f32 elements): x | new_rnn_states | h_stack | c_stack
#define OUT_RNN  33554432u
#define OUT_HS   34603008u
#define OUT_CS   68157440u

typedef __attribute__((ext_vector_type(4))) float f32x4;
typedef __attribute__((ext_vector_type(8))) short s16x8;
typedef __attribute__((ext_vector_type(4))) unsigned int u32x4;
typedef __attribute__((ext_vector_type(4))) unsigned short u16x4;

__device__ __forceinline__ unsigned short f2bf(float f) {
  union { float f; unsigned int u; } v; v.f = f;
  return (unsigned short)((v.u + 0x7FFFu + ((v.u >> 16) & 1u)) >> 16);
}
__device__ __forceinline__ float bf2f(unsigned short s) {
  union { unsigned int u; float f; } v; v.u = ((unsigned int)s) << 16;
  return v.f;
}
__device__ __forceinline__ unsigned int pack2(float a, float b) {
  return (unsigned int)f2bf(a) | ((unsigned int)f2bf(b) << 16);
}
__device__ __forceinline__ float sigm(float x) { return 1.0f / (1.0f + __expf(-x)); }

__device__ __forceinline__ void gl_lds16(const void* g, void* lds) {
  __builtin_amdgcn_global_load_lds(
      (const __attribute__((address_space(1))) unsigned int*)g,
      (__attribute__((address_space(3))) unsigned int*)lds, 16, 0, 0);
}

// Fragment conventions (16x16x32 bf16 MFMA):
//  A/B input frag (1KB): lane l holds index (l&15) of the 16-dim, k = ks*32+(l>>4)*8+e.
//  D frag: col = l&15 (B dim), row = (l>>4)*4 + reg (A dim).  [m89-verified]

// ====================== FAST PATH ======================

__global__ void __launch_bounds__(256) prep_fast(
    const float* __restrict__ xg, const float* __restrict__ rnn,
    const float* __restrict__ Wih, const float* __restrict__ Whh,
    const float* __restrict__ bih, const float* __restrict__ bhh,
    unsigned char* __restrict__ ws) {
  unsigned int tid = blockIdx.x * 256u + threadIdx.x;
  unsigned short* wih_f = (unsigned short*)(ws + F_WIH);
  unsigned short* whh_f = (unsigned short*)(ws + F_WHH);
  unsigned short* hf    = (unsigned short*)(ws + F_HF);
  float* cf   = (float*)(ws + F_CF);
  float* bias = (float*)(ws + F_BIAS);
  unsigned short* xbf = (unsigned short*)(ws + F_XBF);
  if (tid < 131072u) {
    unsigned int frag = tid >> 6, l = tid & 63u;
    unsigned int cb = frag >> 4, ks = frag & 15u;
    unsigned int g  = cb * 16u + (l & 15u);
    unsigned int k0 = ks * 32u + ((l >> 4) << 3);
    const float* src = Wih + (size_t)g * 512u + k0;
    u32x4 p;
    p.x = pack2(src[0], src[1]); p.y = pack2(src[2], src[3]);
    p.z = pack2(src[4], src[5]); p.w = pack2(src[6], src[7]);
    *(u32x4*)(wih_f + (size_t)frag * 512u + l * 8u) = p;
  } else if (tid < 262144u) {
    unsigned int t2 = tid - 131072u;
    unsigned int frag = t2 >> 6, l = t2 & 63u;
    unsigned int cb = frag >> 4, ks = frag & 15u;
    unsigned int g  = cb * 16u + (l & 15u);
    unsigned int k0 = ks * 32u + ((l >> 4) << 3);
    const float* src = Whh + (size_t)g * 512u + k0;
    u32x4 p;
    p.x = pack2(src[0], src[1]); p.y = pack2(src[2], src[3]);
    p.z = pack2(src[4], src[5]); p.w = pack2(src[6], src[7]);
    *(u32x4*)(whh_f + (size_t)frag * 512u + l * 8u) = p;
  } else if (tid < 327680u) {
    unsigned int t2 = tid - 262144u;
    unsigned int frag = t2 >> 6, l = t2 & 63u;
    unsigned int mb = frag >> 4, ks = frag & 15u;
    unsigned int b  = mb * 16u + (l & 15u);
    unsigned int c0 = ks * 32u + ((l >> 4) << 3);
    const float* src = rnn + (size_t)b * 1024u + c0;
    u32x4 p;
    p.x = pack2(src[0], src[1]); p.y = pack2(src[2], src[3]);
    p.z = pack2(src[4], src[5]); p.w = pack2(src[6], src[7]);
    *(u32x4*)(hf + (size_t)frag * 512u + l * 8u) = p;
  } else if (tid < 458752u) {
    unsigned int t2 = tid - 327680u;
    unsigned int frag = t2 >> 6, l = t2 & 63u;
    unsigned int mb = frag >> 5, cfi = frag & 31u;
    unsigned int hcol = cfi * 16u + (l & 15u);
    f32x4 p;
    #pragma unroll
    for (int r = 0; r < 4; ++r) {
      unsigned int b = mb * 16u + ((l >> 4) << 2) + r;
      p[r] = rnn[(size_t)b * 1024u + 512u + hcol];
    }
    *(f32x4*)(cf + (size_t)frag * 256u + l * 4u) = p;
  } else if (tid < 460800u) {
    unsigned int g = tid - 458752u;
    bias[g] = bih[g] + bhh[g];
  } else if (tid < 4655104u) {
    unsigned int t2 = tid - 460800u;
    unsigned int frag = t2 >> 6, l = t2 & 63u;
    unsigned int ks = frag & 15u, mb = (frag >> 4) & 63u, t = frag >> 10;
    unsigned int b  = mb * 16u + (l & 15u);
    unsigned int k0 = ks * 32u + ((l >> 4) << 3);
    const float* src = xg + ((size_t)(b * 64u + t)) * 512u + k0;
    u32x4 p;
    p.x = pack2(src[0], src[1]); p.y = pack2(src[2], src[3]);
    p.z = pack2(src[4], src[5]); p.w = pack2(src[6], src[7]);
    *(u32x4*)(xbf + (size_t)frag * 512u + l * 8u) = p;
  }
}

// Big GEMM: x_proj[t] = x_t @ W_ih^T + bias, bf16 D-frag output.
// grid 8192 = t(64) x mtile(8) x ntile(16); tile 128M x 128N, K=512, BK=64.
__global__ void __launch_bounds__(256) gemm_xproj(unsigned char* __restrict__ ws) {
  const unsigned short* xbf = (const unsigned short*)(ws + F_XBF);
  const unsigned short* wih = (const unsigned short*)(ws + F_WIH);
  const float* bias = (const float*)(ws + F_BIAS);
  unsigned short* xproj = (unsigned short*)(ws + F_XPROJ);

  __shared__ __align__(16) unsigned char smem[65536];
  const int tid = threadIdx.x;
  const int w = tid >> 6, l = tid & 63;
  const int mh = w & 1, nh = w >> 1;
  const int bid = blockIdx.x;
  const int t = bid >> 7, mtile = (bid >> 4) & 7, ntile = bid & 15;

  f32x4 acc[4][4];
  {
    f32x4 z = {0.f, 0.f, 0.f, 0.f};
    #pragma unroll
    for (int i = 0; i < 4; ++i)
      #pragma unroll
      for (int j = 0; j < 4; ++j) acc[i][j] = z;
  }

  auto stage = [&](int kc, int buf) {
    unsigned char* ab = smem + buf * 16384;
    unsigned char* bb = smem + 32768 + buf * 16384;
    #pragma unroll
    for (int j = 0; j < 4; ++j) {
      int idx = w * 4 + j;
      int mb_l = idx >> 1, ksl = idx & 1;
      size_t frag = (size_t)(t * 64 + mtile * 8 + mb_l) * 16u + kc * 2 + ksl;
      gl_lds16(xbf + (frag * 64u + l) * 8u, ab + idx * 1024);
    }
    #pragma unroll
    for (int j = 0; j < 4; ++j) {
      int idx = w * 4 + j;
      int cb_l = idx >> 1, ksl = idx & 1;
      size_t frag = (size_t)(ntile * 8 + cb_l) * 16u + kc * 2 + ksl;
      gl_lds16(wih + (frag * 64u + l) * 8u, bb + idx * 1024);
    }
  };

  stage(0, 0);
  __syncthreads();
  for (int kc = 0; kc < 8; ++kc) {
    int cur = kc & 1;
    if (kc < 7) stage(kc + 1, cur ^ 1);
    unsigned char* ab = smem + cur * 16384;
    unsigned char* bb = smem + 32768 + cur * 16384;
    s16x8 afr[4][2], bfr[4][2];
    #pragma unroll
    for (int m = 0; m < 4; ++m)
      #pragma unroll
      for (int ksl = 0; ksl < 2; ++ksl)
        afr[m][ksl] = *(const s16x8*)(ab + ((mh * 4 + m) * 2 + ksl) * 1024 + l * 16);
    #pragma unroll
    for (int n = 0; n < 4; ++n)
      #pragma unroll
      for (int ksl = 0; ksl < 2; ++ksl)
        bfr[n][ksl] = *(const s16x8*)(bb + ((nh * 4 + n) * 2 + ksl) * 1024 + l * 16);
    #pragma unroll
    for (int m = 0; m < 4; ++m)
      #pragma unroll
      for (int n = 0; n < 4; ++n)
        #pragma unroll
        for (int ksl = 0; ksl < 2; ++ksl)
          acc[m][n] = __builtin_amdgcn_mfma_f32_16x16x32_bf16(
              afr[m][ksl], bfr[n][ksl], acc[m][n], 0, 0, 0);
    __syncthreads();
  }

  #pragma unroll
  for (int m = 0; m < 4; ++m) {
    int mb_abs = mtile * 8 + mh * 4 + m;
    #pragma unroll
    for (int n = 0; n < 4; ++n) {
      int n_abs = ntile * 8 + nh * 4 + n;
      float bc = bias[n_abs * 16 + (l & 15)];
      u16x4 p;
      #pragma unroll
      for (int r = 0; r < 4; ++r) p[r] = f2bf(acc[m][n][r] + bc);
      *(u16x4*)(xproj + ((size_t)(t * 64 + mb_abs) * 128u + n_abs) * 256u + l * 4u) = p;
    }
  }
}

// Step: gates = x_proj[t] + h @ W_hh^T (K=512). grid 256 = mt(16) x ht(16).
// Barrier-free main loop: full W-tile in LDS (128KB, staged once), A in VGPRs.
__global__ void __launch_bounds__(256, 1) step_fast(
    const float* __restrict__ dones, unsigned char* __restrict__ ws,
    float* __restrict__ out, int t) {
  const unsigned short* whh = (const unsigned short*)(ws + F_WHH);
  unsigned short* hf = (unsigned short*)(ws + F_HF);
  float* cf = (float*)(ws + F_CF);
  const unsigned short* xproj = (const unsigned short*)(ws + F_XPROJ);

  __shared__ __align__(16) unsigned char smem[131072];  // 128 B-frags
  const int tid = threadIdx.x;
  const int w = tid >> 6, l = tid & 63;
  const int mh = w & 1, ch = w >> 1;
  const int mt = (int)blockIdx.x >> 4, ht = (int)blockIdx.x & 15;

  // 1) stage full W_hh tile -> LDS: 128 frags, 32 per wave.
  //    slot = ((g*2+cbl)*16 + ks)*1024 ; cb = (g)*32 + ht*2 + cbl
  #pragma unroll
  for (int j = 0; j < 32; ++j) {
    int idx = w * 32 + j;
    int gcb = idx >> 4, ks = idx & 15;
    int cb = (gcb >> 1) * 32 + ht * 2 + (gcb & 1);
    gl_lds16(whh + ((size_t)(cb * 16 + ks) * 64u + l) * 8u, smem + idx * 1024);
  }

  // 2) A operand (h frags) straight to registers: 2 mb x 16 ks per wave.
  s16x8 areg[2][16];
  #pragma unroll
  for (int mb2 = 0; mb2 < 2; ++mb2) {
    int frag0 = (mt * 4 + mh * 2 + mb2) * 16;
    #pragma unroll
    for (int ks = 0; ks < 16; ++ks)
      areg[mb2][ks] = *(const s16x8*)(hf + ((size_t)(frag0 + ks) * 64u + l) * 8u);
  }

  // 3) preload epilogue data (hide latency under MFMA loop)
  u16x4 xpv[2][4];
  f32x4 cold[2];
  f32x4 kv[2];
  const int cfi = ht * 2 + ch;
  #pragma unroll
  for (int mb2 = 0; mb2 < 2; ++mb2) {
    const int mb_abs = mt * 4 + mh * 2 + mb2;
    #pragma unroll
    for (int g = 0; g < 4; ++g) {
      int n_abs = g * 32 + ht * 2 + ch;
      xpv[mb2][g] = *(const u16x4*)(xproj +
          ((size_t)(t * 64 + mb_abs) * 128u + n_abs) * 256u + l * 4u);
    }
    cold[mb2] = *(const f32x4*)(cf + (size_t)(mb_abs * 32 + cfi) * 256u + l * 4u);
    #pragma unroll
    for (int r = 0; r < 4; ++r) {
      int brow = mb_abs * 16 + ((l >> 4) << 2) + r;
      kv[mb2][r] = dones[brow * 64 + t];
    }
  }
  const float keep2 = 1.0f - dones[(mt * 64 + (tid >> 6) * 16 + (tid & 15)) * 64 + t];

  f32x4 acc[2][4];
  {
    f32x4 z = {0.f, 0.f, 0.f, 0.f};
    #pragma unroll
    for (int i = 0; i < 2; ++i)
      #pragma unroll
      for (int j = 0; j < 4; ++j) acc[i][j] = z;
  }

  __syncthreads();  // single drain: W tile resident, A regs loaded

  // 4) barrier-free K loop: 64 ds_read_b128 + 128 MFMA, freely schedulable
  #pragma unroll
  for (int kc = 0; kc < 8; ++kc) {
    s16x8 bfr[4][2];
    #pragma unroll
    for (int g = 0; g < 4; ++g)
      #pragma unroll
      for (int ksl = 0; ksl < 2; ++ksl)
        bfr[g][ksl] = *(const s16x8*)(smem +
            (((g * 2 + ch) * 16) + kc * 2 + ksl) * 1024 + l * 16);
    #pragma unroll
    for (int mb2 = 0; mb2 < 2; ++mb2)
      #pragma unroll
      for (int g = 0; g < 4; ++g)
        #pragma unroll
        for (int ksl = 0; ksl < 2; ++ksl)
          acc[mb2][g] = __builtin_amdgcn_mfma_f32_16x16x32_bf16(
              areg[mb2][kc * 2 + ksl], bfr[g][ksl], acc[mb2][g], 0, 0, 0);
  }

  // add x_proj (bias folded in)
  #pragma unroll
  for (int mb2 = 0; mb2 < 2; ++mb2)
    #pragma unroll
    for (int g = 0; g < 4; ++g)
      #pragma unroll
      for (int r = 0; r < 4; ++r)
        acc[mb2][g][r] += bf2f(xpv[mb2][g][r]);

  __syncthreads();  // all B ds_reads done before smem reuse for Hl/Cl

  // ---- LSTM cell, state update (fold next-step mask), outputs ----
  float* Hl = (float*)smem;            // [64][36] f32
  float* Cl = (float*)(smem + 9216);   // [64][36] f32
  const int colL = ch * 16 + (l & 15);
  #pragma unroll
  for (int mb2 = 0; mb2 < 2; ++mb2) {
    const int mb_abs = mt * 4 + mh * 2 + mb2;
    const int fid = mb_abs * 32 + cfi;
    f32x4 cmask;
    #pragma unroll
    for (int r = 0; r < 4; ++r) {
      float gi = sigm(acc[mb2][0][r]);
      float gf = sigm(acc[mb2][1][r]);
      float gg = tanhf(acc[mb2][2][r]);
      float go = sigm(acc[mb2][3][r]);
      float c = gf * cold[mb2][r] + gi * gg;
      float h = go * tanhf(c);
      float keep = 1.0f - kv[mb2][r];
      cmask[r] = c * keep;
      int rowL = mh * 32 + mb2 * 16 + ((l >> 4) << 2) + r;
      Hl[rowL * 36 + colL] = h;
      Cl[rowL * 36 + colL] = c;
    }
    *(f32x4*)(cf + (size_t)fid * 256u + l * 4u) = cmask;
  }
  __syncthreads();

  {  // repack masked h into frag-major bf16 state (next step's A)
    const int mb2f = tid >> 6, lp = tid & 63;
    const int mb_abs = mt * 4 + mb2f;
    const int rowL = mb2f * 16 + (lp & 15);
    const int c0 = (lp >> 4) << 3;
    const float* hr = Hl + rowL * 36 + c0;
    u32x4 p;
    p.x = pack2(hr[0] * keep2, hr[1] * keep2);
    p.y = pack2(hr[2] * keep2, hr[3] * keep2);
    p.z = pack2(hr[4] * keep2, hr[5] * keep2);
    p.w = pack2(hr[6] * keep2, hr[7] * keep2);
    *(u32x4*)(hf + ((size_t)(mb_abs * 16 + ht) * 64u + lp) * 8u) = p;
  }
  {  // coalesced f32 outputs
    const int row = tid & 63, cg = tid >> 6;
    const int b = mt * 64 + row;
    const int c0 = cg * 8;
    const float* hr = Hl + row * 36 + c0;
    const float* cr = Cl + row * 36 + c0;
    f32x4 h0 = *(const f32x4*)hr,  h1 = *(const f32x4*)(hr + 4);
    f32x4 cc0 = *(const f32x4*)cr, cc1 = *(const f32x4*)(cr + 4);
    const int colg = ht * 32 + c0;
    size_t xoff = ((size_t)(b * 64 + t)) * 512u + colg;
    *(f32x4*)(out + xoff) = h0; *(f32x4*)(out + xoff + 4) = h1;
    size_t hoff = OUT_HS + ((size_t)(t * 1024 + b)) * 512u + colg;
    *(f32x4*)(out + hoff) = h0; *(f32x4*)(out + hoff + 4) = h1;
    size_t coff = OUT_CS + ((size_t)(t * 1024 + b)) * 512u + colg;
    *(f32x4*)(out + coff) = cc0; *(f32x4*)(out + coff + 4) = cc1;
    if (t == 63) {
      size_t roff = OUT_RNN + (size_t)b * 1024u + colg;
      *(f32x4*)(out + roff) = h0;        *(f32x4*)(out + roff + 4) = h1;
      *(f32x4*)(out + roff + 512) = cc0; *(f32x4*)(out + roff + 516) = cc1;
    }
  }
}

// ====================== FALLBACK (round-1, verified) ======================

__global__ void __launch_bounds__(256) prep_kernel(
    const float* __restrict__ rnn, const float* __restrict__ Wih,
    const float* __restrict__ Whh, const float* __restrict__ bih,
    const float* __restrict__ bhh, unsigned char* __restrict__ ws) {
  unsigned int tid = blockIdx.x * 256u + threadIdx.x;
  unsigned short* wcf = (unsigned short*)(ws + WC_OFF);
  unsigned short* hf  = (unsigned short*)(ws + HF_OFF);
  float* cf   = (float*)(ws + CF_OFF);
  float* bias = (float*)(ws + BIAS_OFF);
  if (tid < 262144u) {
    unsigned int frag = tid >> 6, l = tid & 63u;
    unsigned int cb = frag >> 5, ks = frag & 31u;
    unsigned int g  = cb * 16u + (l & 15u);
    unsigned int k0 = ks * 32u + ((l >> 4) << 3);
    const float* src = (k0 < 512u) ? (Wih + g * 512u + k0) : (Whh + g * 512u + (k0 - 512u));
    u32x4 p;
    p.x = pack2(src[0], src[1]); p.y = pack2(src[2], src[3]);
    p.z = pack2(src[4], src[5]); p.w = pack2(src[6], src[7]);
    *(u32x4*)(wcf + (size_t)frag * 512u + l * 8u) = p;
  } else if (tid < 327680u) {
    unsigned int t2 = tid - 262144u;
    unsigned int frag = t2 >> 6, l = t2 & 63u;
    unsigned int mb = frag >> 4, ks = frag & 15u;
    unsigned int b  = mb * 16u + (l & 15u);
    unsigned int c0 = ks * 32u + ((l >> 4) << 3);
    const float* src = rnn + (size_t)b * 1024u + c0;
    u32x4 p;
    p.x = pack2(src[0], src[1]); p.y = pack2(src[2], src[3]);
    p.z = pack2(src[4], src[5]); p.w = pack2(src[6], src[7]);
    *(u32x4*)(hf + (size_t)frag * 512u + l * 8u) = p;
  } else if (tid < 458752u) {
    unsigned int t2 = tid - 327680u;
    unsigned int frag = t2 >> 6, l = t2 & 63u;
    unsigned int mb = frag >> 5, cfi = frag & 31u;
    unsigned int hcol = cfi * 16u + (l & 15u);
    f32x4 p;
    #pragma unroll
    for (int r = 0; r < 4; ++r) {
      unsigned int b = mb * 16u + ((l >> 4) << 2) + r;
      p[r] = rnn[(size_t)b * 1024u + 512u + hcol];
    }
    *(f32x4*)(cf + (size_t)frag * 256u + l * 4u) = p;
  } else if (tid < 460800u) {
    unsigned int g = tid - 458752u;
    bias[g] = bih[g] + bhh[g];
  }
}

__global__ void __launch_bounds__(256) step_kernel(
    const float* __restrict__ xg, const float* __restrict__ dones,
    unsigned char* __restrict__ ws, float* __restrict__ out, int t) {
  const unsigned short* wcf = (const unsigned short*)(ws + WC_OFF);
  unsigned short* hf = (unsigned short*)(ws + HF_OFF);
  float* cf = (float*)(ws + CF_OFF);
  const float* bias = (const float*)(ws + BIAS_OFF);

  __shared__ __align__(16) unsigned char smem[49152];
  const int tid = threadIdx.x;
  const int w = tid >> 6, l = tid & 63;
  const int mh = w & 1, ch = w >> 1;
  const int mt = (int)blockIdx.x >> 4, ht = (int)blockIdx.x & 15;

  f32x4 acc[2][4];
  {
    f32x4 z = {0.f, 0.f, 0.f, 0.f};
    #pragma unroll
    for (int i = 0; i < 2; ++i)
      #pragma unroll
      for (int j = 0; j < 4; ++j) acc[i][j] = z;
  }

  f32x4 xv[2][2];

  auto stage_load = [&](int kc, int buf) {
    unsigned char* bb = smem + 16384 + buf * 16384;
    #pragma unroll
    for (int j = 0; j < 4; ++j) {
      int idx = w * 4 + j;
      int g = idx >> 2, cbl = (idx >> 1) & 1, ksl = idx & 1;
      int cb = g * 32 + ht * 2 + cbl;
      int ks = kc * 2 + ksl;
      const unsigned short* src = wcf + ((size_t)(cb * 32 + ks) * 64u + l) * 8u;
      gl_lds16(src, bb + idx * 1024);
    }
    unsigned char* ab = smem + buf * 8192;
    if (kc >= 8) {
      #pragma unroll
      for (int j = 0; j < 2; ++j) {
        int idx = w * 2 + j;
        int ksh = (kc - 8) * 2 + j;
        int mb_abs = mt * 4 + w;
        const unsigned short* src = hf + ((size_t)(mb_abs * 16 + ksh) * 64u + l) * 8u;
        gl_lds16(src, ab + idx * 1024);
      }
    } else {
      #pragma unroll
      for (int j = 0; j < 2; ++j) {
        int ks = kc * 2 + j;
        int b = mt * 64 + w * 16 + (l & 15);
        int k0 = ks * 32 + ((l >> 4) << 3);
        const float* src = xg + ((size_t)(b * 64 + t)) * 512u + k0;
        xv[j][0] = *(const f32x4*)src;
        xv[j][1] = *(const f32x4*)(src + 4);
      }
    }
  };
  auto stage_write = [&](int kc, int buf) {
    if (kc < 8) {
      unsigned char* ab = smem + buf * 8192;
      #pragma unroll
      for (int j = 0; j < 2; ++j) {
        int idx = w * 2 + j;
        u32x4 p;
        p.x = pack2(xv[j][0].x, xv[j][0].y); p.y = pack2(xv[j][0].z, xv[j][0].w);
        p.z = pack2(xv[j][1].x, xv[j][1].y); p.w = pack2(xv[j][1].z, xv[j][1].w);
        *(u32x4*)(ab + idx * 1024 + l * 16) = p;
      }
    }
  };

  stage_load(0, 0);
  stage_write(0, 0);
  __syncthreads();

  for (int kc = 0; kc < 16; ++kc) {
    int cur = kc & 1;
    if (kc < 15) stage_load(kc + 1, cur ^ 1);
    unsigned char* ab = smem + cur * 8192;
    unsigned char* bb = smem + 16384 + cur * 16384;
    s16x8 afr[2][2], bfr[4][2];
    #pragma unroll
    for (int mb2 = 0; mb2 < 2; ++mb2)
      #pragma unroll
      for (int ksl = 0; ksl < 2; ++ksl)
        afr[mb2][ksl] = *(const s16x8*)(ab + ((mh * 2 + mb2) * 2 + ksl) * 1024 + l * 16);
    #pragma unroll
    for (int g = 0; g < 4; ++g)
      #pragma unroll
      for (int ksl = 0; ksl < 2; ++ksl)
        bfr[g][ksl] = *(const s16x8*)(bb + (g * 4 + ch * 2 + ksl) * 1024 + l * 16);
    #pragma unroll
    for (int mb2 = 0; mb2 < 2; ++mb2)
      #pragma unroll
      for (int g = 0; g < 4; ++g)
        #pragma unroll
        for (int ksl = 0; ksl < 2; ++ksl)
          acc[mb2][g] = __builtin_amdgcn_mfma_f32_16x16x32_bf16(
              afr[mb2][ksl], bfr[g][ksl], acc[mb2][g], 0, 0, 0);
    if (kc < 15) stage_write(kc + 1, cur ^ 1);
    __syncthreads();
  }

  const int hcol = ht * 32 + ch * 16 + (l & 15);
  const float bi = bias[hcol], bf2 = bias[512 + hcol];
  const float bg = bias[1024 + hcol], bo = bias[1536 + hcol];
  float* Hl = (float*)smem;
  float* Cl = (float*)(smem + 9216);
  const int cfi = ht * 2 + ch;
  const int colL = ch * 16 + (l & 15);
  #pragma unroll
  for (int mb2 = 0; mb2 < 2; ++mb2) {
    const int mb_abs = mt * 4 + mh * 2 + mb2;
    const int fid = mb_abs * 32 + cfi;
    f32x4 cold = *(const f32x4*)(cf + (size_t)fid * 256u + l * 4u);
    f32x4 cmask;
    #pragma unroll
    for (int r = 0; r < 4; ++r) {
      float gi = sigm(acc[mb2][0][r] + bi);
      float gf = sigm(acc[mb2][1][r] + bf2);
      float gg = tanhf(acc[mb2][2][r] + bg);
      float go = sigm(acc[mb2][3][r] + bo);
      float c = gf * cold[r] + gi * gg;
      float h = go * tanhf(c);
      int brow = mb_abs * 16 + ((l >> 4) << 2) + r;
      float keep = 1.0f - dones[brow * 64 + t];
      cmask[r] = c * keep;
      int rowL = mh * 32 + mb2 * 16 + ((l >> 4) << 2) + r;
      Hl[rowL * 36 + colL] = h;
      Cl[rowL * 36 + colL] = c;
    }
    *(f32x4*)(cf + (size_t)fid * 256u + l * 4u) = cmask;
  }
  __syncthreads();

  {
    const int mb2f = tid >> 6, lp = tid & 63;
    const int mb_abs = mt * 4 + mb2f;
    const int rowL = mb2f * 16 + (lp & 15);
    const int c0 = (lp >> 4) << 3;
    const int brow = mt * 64 + rowL;
    const float keep = 1.0f - dones[brow * 64 + t];
    const float* hr = Hl + rowL * 36 + c0;
    u32x4 p;
    p.x = pack2(hr[0] * keep, hr[1] * keep);
    p.y = pack2(hr[2] * keep, hr[3] * keep);
    p.z = pack2(hr[4] * keep, hr[5] * keep);
    p.w = pack2(hr[6] * keep, hr[7] * keep);
    *(u32x4*)(hf + ((size_t)(mb_abs * 16 + ht) * 64u + lp) * 8u) = p;
  }
  {
    const int row = tid & 63, cg = tid >> 6;
    const int b = mt * 64 + row;
    const int c0 = cg * 8;
    const float* hr = Hl + row * 36 + c0;
    const float* cr = Cl + row * 36 + c0;
    f32x4 h0 = *(const f32x4*)hr,  h1 = *(const f32x4*)(hr + 4);
    f32x4 cc0 = *(const f32x4*)cr, cc1 = *(const f32x4*)(cr + 4);
    const int colg = ht * 32 + c0;
    size_t xoff = ((size_t)(b * 64 + t)) * 512u + colg;
    *(f32x4*)(out + xoff) = h0; *(f32x4*)(out + xoff + 4) = h1;
    size_t hoff = OUT_HS + ((size_t)(t * 1024 + b)) * 512u + colg;
    *(f32x4*)(out + hoff) = h0; *(f32x4*)(out + hoff + 4) = h1;
    size_t coff = OUT_CS + ((size_t)(t * 1024 + b)) * 512u + colg;
    *(f32x4*)(out + coff) = cc0; *(f32x4*)(out + coff + 4) = cc1;
    if (t == 63) {
      size_t roff = OUT_RNN + (size_t)b * 1024u + colg;
      *(f32x4*)(out + roff) = h0;        *(f32x4*)(out + roff + 4) = h1;
      *(f32x4*)(out + roff + 512) = cc0; *(f32x4*)(out + roff + 516) = cc1;
    }
  }
}

extern "C" void kernel_launch(void* const* d_in, const int* in_sizes, int n_in,
                              void* d_out, int out_size, void* d_ws, size_t ws_size,
                              hipStream_t stream) {
  const float* xg  = (const float*)d_in[0];
  const float* rnn = (const float*)d_in[1];
  const float* dn  = (const float*)d_in[2];
  const float* Wih = (const float*)d_in[3];
  const float* Whh = (const float*)d_in[4];
  const float* bih = (const float*)d_in[5];
  const float* bhh = (const float*)d_in[6];
  float* out = (float*)d_out;
  unsigned char* ws = (unsigned char*)d_ws;
  (void)in_sizes; (void)n_in; (void)out_size;

  if (ws_size >= (size_t)F_NEED) {
    prep_fast<<<18184, 256, 0, stream>>>(xg, rnn, Wih, Whh, bih, bhh, ws);
    gemm_xproj<<<8192, 256, 0, stream>>>(ws);
    for (int t = 0; t < 64; ++t)
      step_fast<<<256, 256, 0, stream>>>(dn, ws, out, t);
  } else {
    prep_kernel<<<1800, 256, 0, stream>>>(rnn, Wih, Whh, bih, bhh, ws);
    for (int t = 0; t < 64; ++t)
      step_kernel<<<256, 256, 0, stream>>>(xg, dn, ws, out, t);
  }
}